// Round 4
// baseline (57.591 us; speedup 1.0000x reference)
//
#include <hip/hip_runtime.h>
#include <hip/hip_bf16.h>

// Fully fused MLP: 32 -> 64 -> (4x) 64 -> 3, relu hidden, sigmoid out.
// bf16 MFMA (16x16x32), fp32 accum, operand-swapped (D[neuron][point] = W*H).
// Point index is lane-invariant across layers; neuron relabeling pi baked into
// next-layer weight columns at prep time -> lane-local layer handoff, no LDS
// round-trip for activations.
//
// Round-4: LDS weight traffic was the bottleneck (59KB re-read per 32 points;
// ~60-90k cyc/CU vs MFMA's 47k). Changes:
//  - 4 tiles (64 points) per weight read (halves LDS bytes/point)
//  - pair-staged hidden layers to keep VGPR <= 128 (2 blocks/CU = 16 waves)
//  - layer loop fully unrolled; x prefetch for it+1 issued during output phase
//  - packed 12B output stores
//
// Frag map: 0..3 W_in[nt] | 4..35 W_hid[L][nt][f] | 36..37 W_out[f]
//           38..41 b_in[nt] | 42..57 b_hid[L][nt] | 58 b_out

typedef __attribute__((ext_vector_type(8))) short bf16x8;
typedef __attribute__((ext_vector_type(4))) float f32x4;

#define NFRAG 59
#define IMG_U4 (NFRAG * 64)          // 3776 uint4 = 60416 B

struct F3 { float a, b, c; };        // 12B packed output store

// packed f32x2 -> bf16x2, RNE, 1 instruction. lo = low 16 bits.
__device__ __forceinline__ unsigned cvtpk(float lo, float hi) {
    unsigned r;
    asm("v_cvt_pk_bf16_f32 %0, %1, %2" : "=v"(r) : "v"(lo), "v"(hi));
    return r;
}

// inverse of the neuron relabeling pi: k-slot s -> actual neuron index
__device__ __forceinline__ int pinv(int s) {
    return ((s >> 5) & 1) * 32 + ((s >> 2) & 1) * 16 + ((s >> 3) & 3) * 4 + (s & 3);
}

// value of image slot (frag F, lane) computed from the fp32 weights
__device__ uint4 frag_value(int F, int lane,
        const float* __restrict__ W_in,  const float* __restrict__ b_in,
        const float* __restrict__ W_hid, const float* __restrict__ b_hid,
        const float* __restrict__ W_out, const float* __restrict__ b_out) {
    const int j = lane & 15, g = lane >> 4;
    uint4 r = {0u, 0u, 0u, 0u};
    if (F < 4) {                                   // W_in A-frag, natural k
        const float* row = W_in + (F * 16 + j) * 32 + 8 * g;
        r.x = cvtpk(row[0], row[1]); r.y = cvtpk(row[2], row[3]);
        r.z = cvtpk(row[4], row[5]); r.w = cvtpk(row[6], row[7]);
    } else if (F < 36) {                           // W_hid A-frag, pi-relabeled k
        int q = F - 4, L = q >> 3, nt = (q >> 1) & 3, f = q & 1;
        const float* row = W_hid + (L * 64 + nt * 16 + j) * 64;
        int s0 = 32 * f + 8 * g;
        r.x = cvtpk(row[pinv(s0 + 0)], row[pinv(s0 + 1)]);
        r.y = cvtpk(row[pinv(s0 + 2)], row[pinv(s0 + 3)]);
        r.z = cvtpk(row[pinv(s0 + 4)], row[pinv(s0 + 5)]);
        r.w = cvtpk(row[pinv(s0 + 6)], row[pinv(s0 + 7)]);
    } else if (F < 38) {                           // W_out A-frag (rows 3..15 zero)
        int f = F - 36;
        if (j < 3) {
            const float* row = W_out + j * 64;
            int s0 = 32 * f + 8 * g;
            r.x = cvtpk(row[pinv(s0 + 0)], row[pinv(s0 + 1)]);
            r.y = cvtpk(row[pinv(s0 + 2)], row[pinv(s0 + 3)]);
            r.z = cvtpk(row[pinv(s0 + 4)], row[pinv(s0 + 5)]);
            r.w = cvtpk(row[pinv(s0 + 6)], row[pinv(s0 + 7)]);
        }
    } else {                                       // bias C-frags: f32x4, row = 4g+rr
        union { uint4 u; float f[4]; } t;
        if (F < 42) {
            int nt = F - 38;
#pragma unroll
            for (int rr = 0; rr < 4; ++rr) t.f[rr] = b_in[nt * 16 + 4 * g + rr];
        } else if (F < 58) {
            int q = F - 42, L = q >> 2, nt = q & 3;
#pragma unroll
            for (int rr = 0; rr < 4; ++rr) t.f[rr] = b_hid[L * 64 + nt * 16 + 4 * g + rr];
        } else {
#pragma unroll
            for (int rr = 0; rr < 4; ++rr) t.f[rr] = (4 * g + rr < 3) ? b_out[4 * g + rr] : 0.f;
        }
        r = t.u;
    }
    return r;
}

__global__ void prep_kernel(const float* __restrict__ W_in,  const float* __restrict__ b_in,
                            const float* __restrict__ W_hid, const float* __restrict__ b_hid,
                            const float* __restrict__ W_out, const float* __restrict__ b_out,
                            uint4* __restrict__ img) {
    img[blockIdx.x * 64 + threadIdx.x] =
        frag_value(blockIdx.x, threadIdx.x, W_in, b_in, W_hid, b_hid, W_out, b_out);
}

// relu + lane-local pi-pack: acc[4] (f32x4) -> h[2] (bf16x8)
__device__ __forceinline__ void relu_pack(const f32x4 a[4], bf16x8 h[2]) {
#pragma unroll
    for (int f = 0; f < 2; ++f) {
        union { bf16x8 v; unsigned u[4]; } t;
        t.u[0] = cvtpk(fmaxf(a[2 * f][0], 0.f), fmaxf(a[2 * f][1], 0.f));
        t.u[1] = cvtpk(fmaxf(a[2 * f][2], 0.f), fmaxf(a[2 * f][3], 0.f));
        t.u[2] = cvtpk(fmaxf(a[2 * f + 1][0], 0.f), fmaxf(a[2 * f + 1][1], 0.f));
        t.u[3] = cvtpk(fmaxf(a[2 * f + 1][2], 0.f), fmaxf(a[2 * f + 1][3], 0.f));
        h[f] = t.v;
    }
}

#define MFMA(a, b, c) __builtin_amdgcn_mfma_f32_16x16x32_bf16((a), (b), (c), 0, 0, 0)

template<bool FAST>
__global__ __launch_bounds__(512, 4) void mlp_kernel(
        const float* __restrict__ x, const uint4* __restrict__ img,
        const float* __restrict__ gW_in,  const float* __restrict__ gb_in,
        const float* __restrict__ gW_hid, const float* __restrict__ gb_hid,
        const float* __restrict__ gW_out, const float* __restrict__ gb_out,
        float* __restrict__ out) {
    __shared__ uint4 simg[IMG_U4];
    const int tid = threadIdx.x;

    if (FAST) {
#pragma unroll
        for (int i = 0; i < 8; ++i) {
            int idx = tid + i * 512;
            if (idx < IMG_U4) simg[idx] = img[idx];
        }
    } else {
        for (int idx = tid; idx < IMG_U4; idx += 512)
            simg[idx] = frag_value(idx >> 6, idx & 63,
                                   gW_in, gb_in, gW_hid, gb_hid, gW_out, gb_out);
    }

    const int wave = tid >> 6, lane = tid & 63;
    const int j = lane & 15, g = lane >> 4;
    const int base = (blockIdx.x * 8 + wave) * 256;

    // iter-0 x load issued before the barrier (hides under staging)
    f32x4 raw[4][2];
    {
        const float* xp = x + (size_t)(base + j) * 32 + 8 * g;
#pragma unroll
        for (int t = 0; t < 4; ++t) {
            raw[t][0] = *(const f32x4*)(xp + t * 512);
            raw[t][1] = *(const f32x4*)(xp + t * 512 + 4);
        }
    }
    __syncthreads();

    const uint4* lp = &simg[lane];     // frag F at lp[F*64]: lane*16 + imm, conflict-free

#pragma unroll 1
    for (int it = 0; it < 4; ++it) {
        const int p0 = base + it * 64;

        // pack current x into B-frags (raw regs die here)
        bf16x8 xf[4];
#pragma unroll
        for (int t = 0; t < 4; ++t) {
            union { bf16x8 v; unsigned u[4]; } a;
            a.u[0] = cvtpk(raw[t][0][0], raw[t][0][1]);
            a.u[1] = cvtpk(raw[t][0][2], raw[t][0][3]);
            a.u[2] = cvtpk(raw[t][1][0], raw[t][1][1]);
            a.u[3] = cvtpk(raw[t][1][2], raw[t][1][3]);
            xf[t] = a.v;
        }

        // ======== input layer: all 4 tiles ========
        bf16x8 hfrag[4][2];
        {
            f32x4 acc[4][4];
#pragma unroll
            for (int nt = 0; nt < 4; ++nt) {
                bf16x8 w  = *(const bf16x8*)&lp[nt * 64];
                f32x4  bz = *(const f32x4*)&lp[(38 + nt) * 64];
#pragma unroll
                for (int t = 0; t < 4; ++t)
                    acc[t][nt] = MFMA(w, xf[t], bz);
            }
#pragma unroll
            for (int t = 0; t < 4; ++t) relu_pack(acc[t], hfrag[t]);
        }

        // ======== 4 hidden layers: weights read once, tiles pair-staged ========
#pragma unroll
        for (int L = 0; L < 4; ++L) {
            const int wb = (4 + L * 8) * 64;
            const int bb = (42 + L * 4) * 64;
            bf16x8 w0[4], w1[4]; f32x4 bz[4];
#pragma unroll
            for (int nt = 0; nt < 4; ++nt) {
                w0[nt] = *(const bf16x8*)&lp[wb + (2 * nt) * 64];
                w1[nt] = *(const bf16x8*)&lp[wb + (2 * nt + 1) * 64];
                bz[nt] = *(const f32x4*)&lp[bb + nt * 64];
            }
#pragma unroll
            for (int pr = 0; pr < 2; ++pr) {
                f32x4 pa[2][4];
#pragma unroll
                for (int q = 0; q < 2; ++q)
#pragma unroll
                    for (int nt = 0; nt < 4; ++nt)
                        pa[q][nt] = MFMA(w0[nt], hfrag[2 * pr + q][0], bz[nt]);
#pragma unroll
                for (int q = 0; q < 2; ++q)
#pragma unroll
                    for (int nt = 0; nt < 4; ++nt)
                        pa[q][nt] = MFMA(w1[nt], hfrag[2 * pr + q][1], pa[q][nt]);
#pragma unroll
                for (int q = 0; q < 2; ++q) relu_pack(pa[q], hfrag[2 * pr + q]);
            }
        }

        // ======== output layer ========
        bf16x8 wo0 = *(const bf16x8*)&lp[36 * 64];
        bf16x8 wo1 = *(const bf16x8*)&lp[37 * 64];
        f32x4  bo  = *(const f32x4*)&lp[58 * 64];
        f32x4 z[4];
#pragma unroll
        for (int t = 0; t < 4; ++t) {
            f32x4 tmp = MFMA(wo0, hfrag[t][0], bo);
            z[t] = MFMA(wo1, hfrag[t][1], tmp);
        }

        // prefetch next iter's x (raw regs were dead since pack)
        {
            const int pn = (it < 3) ? p0 + 64 : p0;
            const float* xp = x + (size_t)(pn + j) * 32 + 8 * g;
#pragma unroll
            for (int t = 0; t < 4; ++t) {
                raw[t][0] = *(const f32x4*)(xp + t * 512);
                raw[t][1] = *(const f32x4*)(xp + t * 512 + 4);
            }
        }

        // sigmoid + packed 12B stores (rows 0..2 live in g==0)
        if (g == 0) {
            float* ob = out + (size_t)(p0 + j) * 3;
#pragma unroll
            for (int t = 0; t < 4; ++t) {
                F3 v;
                v.a = __builtin_amdgcn_rcpf(1.f + __expf(-z[t][0]));
                v.b = __builtin_amdgcn_rcpf(1.f + __expf(-z[t][1]));
                v.c = __builtin_amdgcn_rcpf(1.f + __expf(-z[t][2]));
                *(F3*)(ob + t * 48) = v;
            }
        }
    }
}

extern "C" void kernel_launch(void* const* d_in, const int* in_sizes, int n_in,
                              void* d_out, int out_size, void* d_ws, size_t ws_size,
                              hipStream_t stream) {
    const float* x     = (const float*)d_in[0];
    const float* W_in  = (const float*)d_in[1];
    const float* b_in  = (const float*)d_in[2];
    const float* W_hid = (const float*)d_in[3];
    const float* b_hid = (const float*)d_in[4];
    const float* W_out = (const float*)d_in[5];
    const float* b_out = (const float*)d_in[6];
    float* out = (float*)d_out;

    int n = in_sizes[0] / 32;              // 1<<20 points
    int nblocks = n / 2048;                // 8 waves * 256 points per block = 512 blocks

    if (ws_size >= (size_t)IMG_U4 * 16) {
        hipLaunchKernelGGL(prep_kernel, dim3(NFRAG), dim3(64), 0, stream,
                           W_in, b_in, W_hid, b_hid, W_out, b_out, (uint4*)d_ws);
        hipLaunchKernelGGL((mlp_kernel<true>), dim3(nblocks), dim3(512), 0, stream,
                           x, (const uint4*)d_ws,
                           W_in, b_in, W_hid, b_hid, W_out, b_out, out);
    } else {
        hipLaunchKernelGGL((mlp_kernel<false>), dim3(nblocks), dim3(512), 0, stream,
                           x, (const uint4*)d_ws,
                           W_in, b_in, W_hid, b_hid, W_out, b_out, out);
    }
}